// Round 10
// baseline (106.156 us; speedup 1.0000x reference)
//
#include <hip/hip_runtime.h>
#include <math.h>

typedef unsigned short u16;
typedef __attribute__((ext_vector_type(8))) short s16x8;
typedef __attribute__((ext_vector_type(4))) float f32x4;

#define NROWS 32768
#define DDIM 512
#define HALF 16384
#define KB 64
#define CSLICE 4
#define NSLICE 32
#define NSLOG2 5

__device__ __forceinline__ u16 f2bf(float f) {
  unsigned int u = __float_as_uint(f);
  unsigned int rounding = 0x7FFFu + ((u >> 16) & 1u);
  u += rounding;
  return (u16)(u >> 16);
}

__device__ __forceinline__ float block_reduce(float v) {
  #pragma unroll
  for (int o = 32; o > 0; o >>= 1) v += __shfl_down(v, o);
  __shared__ float red[4];
  int w = threadIdx.x >> 6;
  if ((threadIdx.x & 63) == 0) red[w] = v;
  __syncthreads();
  return red[0] + red[1] + red[2] + red[3];
}

// Kernel 0: inverse permutation. inv[perm[i]] = i.
__global__ void inv_kernel(const int* __restrict__ perm, int* __restrict__ inv) {
  int i = blockIdx.x * 256 + threadIdx.x;
  inv[perm[i]] = i;
}

__device__ __forceinline__ float chunk_proc(float4 a0, float4 a1, float4 b0, float4 b1,
                                            int r, int c8, u16* z1, u16* z2) {
  uint4 o;
  o.x = (unsigned)f2bf(a0.x) | ((unsigned)f2bf(a0.y) << 16);
  o.y = (unsigned)f2bf(a0.z) | ((unsigned)f2bf(a0.w) << 16);
  o.z = (unsigned)f2bf(a1.x) | ((unsigned)f2bf(a1.y) << 16);
  o.w = (unsigned)f2bf(a1.z) | ((unsigned)f2bf(a1.w) << 16);
  u16* dst = (r < HALF) ? (z1 + (size_t)r * DDIM + c8) : (z2 + (size_t)(r - HALF) * DDIM + c8);
  *reinterpret_cast<uint4*>(dst) = o;
  float dx = a0.x - b0.x, dy = a0.y - b0.y, dz = a0.z - b0.z, dw = a0.w - b0.w;
  float ex = a1.x - b1.x, ey = a1.y - b1.y, ez = a1.z - b1.z, ew = a1.w - b1.w;
  return dx*dx + dy*dy + dz*dz + dw*dw + ex*ex + ey*ey + ez*ez + ew*ew;
}

// Kernel 1: sequential read of z_a/z_b, fused repr partial, bf16 convert, scattered row
// write into z1/z2 by rank inv[row]. At the empirical mixed-stream wall (~3.2 TB/s
// combined R+W across 6 structural variants, rounds 1-9); per-block partials, no atomics.
__global__ __launch_bounds__(256) void scatter_repr_kernel(
    const float* __restrict__ za, const float* __restrict__ zb, const int* __restrict__ inv,
    u16* __restrict__ z1, u16* __restrict__ z2, float* __restrict__ psums) {
  int t = threadIdx.x;
  float acc = 0.0f;
  #pragma unroll
  for (int i = 0; i < 2; ++i) {
    int chunk = (i * 4096 + blockIdx.x) * 256 + t;
    int row = chunk >> 6;
    int c8 = (chunk & 63) << 3;
    const float4* pa = reinterpret_cast<const float4*>(za + (size_t)row * DDIM + c8);
    const float4* pb = reinterpret_cast<const float4*>(zb + (size_t)row * DDIM + c8);
    float4 a0 = pa[0], a1 = pa[1];
    float4 b0 = pb[0], b1 = pb[1];
    int r = inv[row];
    acc += chunk_proc(a0, a1, b0, b1, r, c8, z1, z2);
  }
  float tot = block_reduce(acc);
  if (t == 0) psums[blockIdx.x] = tot;
}

// XOR swizzle: element (k, col) of a KBx128 tile lives at u16 index col*64 + (k ^ sw(col)).
__device__ __forceinline__ int swz(int col) { return (((col >> 3) + col) & 7) << 3; }

__device__ __forceinline__ void store8(u16* lds, int c0, int kp, uint4 v0, uint4 v1) {
  const ushort* h0 = reinterpret_cast<const ushort*>(&v0);
  const ushort* h1 = reinterpret_cast<const ushort*>(&v1);
  #pragma unroll
  for (int j = 0; j < 8; ++j) {
    int col = c0 + j;
    unsigned w = (unsigned)h0[j] | ((unsigned)h1[j] << 16);
    *reinterpret_cast<unsigned*>(lds + col * KB + ((kp ^ swz(col)))) = w;
  }
}

// Kernel 2: gram, upper-triangular 128x128 tiles, reg-staged 2-phase double buffer.
// Epilogue: distributed f32 atomicAdd into zeroed rawG (distinct addresses; 32
// slice-blocks per address spread over the kernel) — replaces the 64 MB bf16
// parts round-trip + reduce_parts launch of rounds 5-9. Full-f32 accumulation.
__global__ __launch_bounds__(256) void gram_kernel(const u16* __restrict__ z1,
                                                   const u16* __restrict__ z2,
                                                   float* __restrict__ rawG) {
  int b = blockIdx.x;
  int mat = b & 1;
  int rest = b >> 1;
  int slice = rest & (NSLICE - 1);
  int tile = rest >> NSLOG2;  // 0..9 upper-tri
  int bi, bj;
  if (tile < 4)      { bi = 0; bj = tile; }
  else if (tile < 7) { bi = 1; bj = tile - 3; }
  else if (tile < 9) { bi = 2; bj = tile - 5; }
  else               { bi = 3; bj = 3; }
  int ti = bi * 128, tj = bj * 128;
  const u16* Z = mat ? z2 : z1;
  bool dual = (ti != tj);
  float* G = rawG + (size_t)mat * (DDIM * DDIM);

  __shared__ u16 ldsA[128 * KB];
  __shared__ u16 ldsB[128 * KB];
  const u16* ldsBp = dual ? ldsB : ldsA;

  int t = threadIdx.x;
  int lane = t & 63;
  int wave = t >> 6;
  int wrow = (wave >> 1) * 64;
  int wcol = (wave & 1) * 64;
  int g = lane >> 4;
  int c = lane & 15;
  int h = lane >> 4;
  int c0 = (lane & 15) << 3;
  int kp0 = 8 * wave + 2 * h;  // even row in [0,32)

  f32x4 acc[4][4];
  #pragma unroll
  for (int m = 0; m < 4; ++m)
    #pragma unroll
    for (int n = 0; n < 4; ++n)
      #pragma unroll
      for (int r = 0; r < 4; ++r) acc[m][n][r] = 0.0f;

  uint4 xa0, xa1, xa2, xa3, xb0, xb1, xb2, xb3;
  uint4 ya0, ya1, ya2, ya3, yb0, yb1, yb2, yb3;

#define GLOAD(p, kkv) { \
    const u16* s0 = Z + (size_t)((kkv) + kp0) * DDIM; \
    const u16* s1 = Z + (size_t)((kkv) + kp0 + 32) * DDIM; \
    p##a0 = *reinterpret_cast<const uint4*>(s0 + ti + c0); \
    p##a1 = *reinterpret_cast<const uint4*>(s0 + DDIM + ti + c0); \
    p##a2 = *reinterpret_cast<const uint4*>(s1 + ti + c0); \
    p##a3 = *reinterpret_cast<const uint4*>(s1 + DDIM + ti + c0); \
    if (dual) { \
      p##b0 = *reinterpret_cast<const uint4*>(s0 + tj + c0); \
      p##b1 = *reinterpret_cast<const uint4*>(s0 + DDIM + tj + c0); \
      p##b2 = *reinterpret_cast<const uint4*>(s1 + tj + c0); \
      p##b3 = *reinterpret_cast<const uint4*>(s1 + DDIM + tj + c0); \
    } }

#define GSTORE(p) { \
    store8(ldsA, c0, kp0, p##a0, p##a1); \
    store8(ldsA, c0, kp0 + 32, p##a2, p##a3); \
    if (dual) { \
      store8(ldsB, c0, kp0, p##b0, p##b1); \
      store8(ldsB, c0, kp0 + 32, p##b2, p##b3); \
    } }

#define COMPUTE() { \
    _Pragma("unroll") \
    for (int ks = 0; ks < KB; ks += 32) { \
      s16x8 afr[4], bfr[4]; \
      _Pragma("unroll") \
      for (int m = 0; m < 4; ++m) { \
        int colA = wrow + m * 16 + c; \
        afr[m] = *reinterpret_cast<const s16x8*>(ldsA + colA * KB + ((ks + 8 * g) ^ swz(colA))); \
        int colB = wcol + m * 16 + c; \
        bfr[m] = *reinterpret_cast<const s16x8*>(ldsBp + colB * KB + ((ks + 8 * g) ^ swz(colB))); \
      } \
      _Pragma("unroll") \
      for (int m = 0; m < 4; ++m) \
        _Pragma("unroll") \
        for (int n = 0; n < 4; ++n) \
          acc[m][n] = __builtin_amdgcn_mfma_f32_16x16x32_bf16(afr[m], bfr[n], acc[m][n], 0, 0, 0); \
    } }

  const int kspan = HALF >> NSLOG2;  // 512
  const int k0 = slice * kspan;
  GLOAD(x, k0);
  for (int kk = k0; kk < k0 + kspan; kk += 2 * KB) {
    __syncthreads();
    GSTORE(x);
    __syncthreads();
    GLOAD(y, kk + KB);
    COMPUTE();
    __syncthreads();
    GSTORE(y);
    __syncthreads();
    if (kk + 2 * KB < k0 + kspan) GLOAD(x, kk + 2 * KB);
    COMPUTE();
  }
#undef GLOAD
#undef GSTORE
#undef COMPUTE

  #pragma unroll
  for (int m = 0; m < 4; ++m)
    #pragma unroll
    for (int n = 0; n < 4; ++n)
      #pragma unroll
      for (int r = 0; r < 4; ++r) {
        int orow = ti + wrow + m * 16 + 4 * g + r;
        int ocol = tj + wcol + n * 16 + c;
        atomicAdd(&G[orow * DDIM + ocol], acc[m][n][r]);
      }
}

// Kernel 3: fixup — scale rawG tri by 1/(half-1), write full symmetric f32 cov
// (transposed scalar stores for the lower off-diag blocks). Replaces reduce_parts.
__global__ void fixup_kernel(const float* __restrict__ rawG, float* __restrict__ cov) {
  int idx = blockIdx.x * 256 + threadIdx.x;  // 0..81919
  int mat = (idx >= 40960) ? 1 : 0;
  int tl = idx - mat * 40960;
  int region = tl >> 12;  // 0..9
  int o = tl & 4095;
  int bi, bj;
  if (region < 4)      { bi = 0; bj = region; }
  else if (region < 7) { bi = 1; bj = region - 3; }
  else if (region < 9) { bi = 2; bj = region - 5; }
  else                 { bi = 3; bj = 3; }
  int r = bi * 128 + (o >> 5);
  int cc = bj * 128 + ((o & 31) << 2);
  size_t pos = (size_t)r * DDIM + cc;
  float4 v = *reinterpret_cast<const float4*>(rawG + (size_t)mat * (DDIM * DDIM) + pos);
  const float inv = 1.0f / 16383.0f;
  v.x *= inv; v.y *= inv; v.z *= inv; v.w *= inv;
  float* cv = cov + (size_t)mat * (DDIM * DDIM);
  *reinterpret_cast<float4*>(cv + pos) = v;
  if (bi != bj) {
    cv[(cc + 0) * DDIM + r] = v.x;
    cv[(cc + 1) * DDIM + r] = v.y;
    cv[(cc + 2) * DDIM + r] = v.z;
    cv[(cc + 3) * DDIM + r] = v.w;
  }
}

// Kernel 4a: partial E tiles. grid = 16x16 tiles x CSLICE k-slices, LDS-staged panels,
// I-subtraction folded into staging. Partials to pcov (reused z1 region).
__global__ __launch_bounds__(256) void covdiff_part_kernel(const float* __restrict__ cov,
                                                           float* __restrict__ pcov) {
  int bid = blockIdx.x;
  int bx = bid & 15, by = (bid >> 4) & 15, sl = bid >> 8;
  int r0 = by * 32, c0 = bx * 32, ks = sl * 128;
  const float* c1 = cov;
  const float* c2 = cov + DDIM * DDIM;
  __shared__ float ldsA[32 * 132];
  __shared__ float ldsB[128 * 33];
  int t = threadIdx.x;
  #pragma unroll
  for (int j = 0; j < 4; ++j) {
    int f4 = t + 256 * j;   // 0..1023
    int row = f4 >> 5;      // 0..31
    int k4 = (f4 & 31) << 2;
    float4 v = *reinterpret_cast<const float4*>(c1 + (size_t)(r0 + row) * DDIM + ks + k4);
    int gr = r0 + row;
    if (gr == ks + k4 + 0) v.x -= 1.f;
    if (gr == ks + k4 + 1) v.y -= 1.f;
    if (gr == ks + k4 + 2) v.z -= 1.f;
    if (gr == ks + k4 + 3) v.w -= 1.f;
    *reinterpret_cast<float4*>(&ldsA[row * 132 + k4]) = v;
  }
  {
    int c = t & 31;
    int kb = t >> 5;  // 0..7
    #pragma unroll
    for (int j = 0; j < 16; ++j) {
      int k = kb + 8 * j;
      float v = c2[(size_t)(ks + k) * DDIM + c0 + c];
      if (ks + k == c0 + c) v -= 1.f;
      ldsB[k * 33 + c] = v;
    }
  }
  __syncthreads();
  int col = t & 31;
  int ty = t >> 5;  // 0..7 -> rows ty*4 + 0..3
  float e0 = 0.f, e1 = 0.f, e2 = 0.f, e3 = 0.f;
  #pragma unroll 4
  for (int k = 0; k < 128; ++k) {
    float bv = ldsB[k * 33 + col];
    e0 = fmaf(ldsA[(ty * 4 + 0) * 132 + k], bv, e0);
    e1 = fmaf(ldsA[(ty * 4 + 1) * 132 + k], bv, e1);
    e2 = fmaf(ldsA[(ty * 4 + 2) * 132 + k], bv, e2);
    e3 = fmaf(ldsA[(ty * 4 + 3) * 132 + k], bv, e3);
  }
  float* P = pcov + (size_t)sl * (DDIM * DDIM);
  P[(r0 + ty * 4 + 0) * DDIM + c0 + col] = e0;
  P[(r0 + ty * 4 + 1) * DDIM + c0 + col] = e1;
  P[(r0 + ty * 4 + 2) * DDIM + c0 + col] = e2;
  P[(r0 + ty * 4 + 3) * DDIM + c0 + col] = e3;
}

// Kernel 4b: sum slices, square, per-block partials to psums2.
__global__ void covred_kernel(const float* __restrict__ pcov, float* __restrict__ psums2) {
  int idx = blockIdx.x * 256 + threadIdx.x;  // 0..65535 float4 slots
  float sx = 0.f, sy = 0.f, sz = 0.f, sw = 0.f;
  #pragma unroll
  for (int j = 0; j < CSLICE; ++j) {
    float4 v = reinterpret_cast<const float4*>(pcov)[idx + j * 65536];
    sx += v.x; sy += v.y; sz += v.z; sw += v.w;
  }
  float q = sx * sx + sy * sy + sz * sz + sw * sw;
  float tot = block_reduce(q);
  if (threadIdx.x == 0) psums2[blockIdx.x] = tot;
}

// Kernel 5: final reduction of 4096 repr partials + 256 frob partials.
__global__ void finalize_kernel(const float* __restrict__ psums,
                                const float* __restrict__ psums2,
                                float* __restrict__ out) {
  int t = threadIdx.x;
  float a = 0.f;
  #pragma unroll
  for (int j = 0; j < 16; ++j) a += psums[t + 256 * j];
  float b = psums2[t];
  float ta = block_reduce(a);
  __syncthreads();
  float tb = block_reduce(b);
  if (t == 0) out[0] = 25.0f * (ta / 16777216.0f) + sqrtf(tb);
}

extern "C" void kernel_launch(void* const* d_in, const int* in_sizes, int n_in,
                              void* d_out, int out_size, void* d_ws, size_t ws_size,
                              hipStream_t stream) {
  const float* za = (const float*)d_in[0];
  const float* zb = (const float*)d_in[1];
  const int* perm = (const int*)d_in[2];
  float* out = (float*)d_out;
  char* ws = (char*)d_ws;

  // workspace: psums(16KB)+psums2(1KB)+pad | rawG(2MB, zeroed) | cov(2MB) | z1,z2(32MB) | inv(128KB)
  float* psums = (float*)ws;                  // 4096 floats
  float* psums2 = (float*)(ws + 16384);       // 256 floats
  size_t off = 20480;
  float* rawG = (float*)(ws + off);
  size_t rawBytes = (size_t)2 * DDIM * DDIM * 4;
  off += rawBytes;
  float* cov = (float*)(ws + off);
  off += (size_t)2 * DDIM * DDIM * 4;
  u16* z1 = (u16*)(ws + off);
  u16* z2 = z1 + (size_t)HALF * DDIM;
  float* pcov = (float*)z1;  // reused after gram consumes z1/z2 (CSLICE*1MB <= 16MB)
  off += (size_t)2 * HALF * DDIM * 2;
  int* inv = (int*)(ws + off);

  (void)hipMemsetAsync(rawG, 0, rawBytes, stream);
  inv_kernel<<<NROWS / 256, 256, 0, stream>>>(perm, inv);
  scatter_repr_kernel<<<4096, 256, 0, stream>>>(za, zb, inv, z1, z2, psums);
  gram_kernel<<<2 * 10 * NSLICE, 256, 0, stream>>>(z1, z2, rawG);
  fixup_kernel<<<320, 256, 0, stream>>>(rawG, cov);
  covdiff_part_kernel<<<16 * 16 * CSLICE, 256, 0, stream>>>(cov, pcov);
  covred_kernel<<<256, 256, 0, stream>>>(pcov, psums2);
  finalize_kernel<<<1, 256, 0, stream>>>(psums, psums2, out);
}

// Round 11
// 86.844 us; speedup vs baseline: 1.2224x; 1.2224x over previous
//
#include <hip/hip_runtime.h>
#include <math.h>

typedef unsigned short u16;
typedef __attribute__((ext_vector_type(8))) short s16x8;
typedef __attribute__((ext_vector_type(4))) float f32x4;

#define NROWS 32768
#define DDIM 512
#define HALF 16384
#define KB 64
#define CSLICE 4
#define NSLICE 32
#define NSLOG2 5

__device__ __forceinline__ unsigned f2bf(float f) {
  unsigned int u = __float_as_uint(f);
  unsigned int rounding = 0x7FFFu + ((u >> 16) & 1u);
  u += rounding;
  return u >> 16;
}

__device__ __forceinline__ float bf2f(u16 h) {
  return __uint_as_float(((unsigned)h) << 16);
}

__device__ __forceinline__ float block_reduce(float v) {
  #pragma unroll
  for (int o = 32; o > 0; o >>= 1) v += __shfl_down(v, o);
  __shared__ float red[4];
  int w = threadIdx.x >> 6;
  if ((threadIdx.x & 63) == 0) red[w] = v;
  __syncthreads();
  return red[0] + red[1] + red[2] + red[3];
}

// Kernel 1: PURE READ. repr partial sums only — no z write, no zc, no inv (gram
// gathers za rows via perm directly). First-ever pure-read streaming datapoint.
__global__ __launch_bounds__(256) void repr_kernel(
    const float* __restrict__ za, const float* __restrict__ zb, float* __restrict__ psums) {
  int tid = blockIdx.x * 256 + threadIdx.x;  // 524288 threads
  const int S = 524288;
  float acc = 0.0f;
  #pragma unroll
  for (int i = 0; i < 8; ++i) {
    size_t idx = (size_t)(i * S + tid);
    float4 a = reinterpret_cast<const float4*>(za)[idx];
    float4 b = reinterpret_cast<const float4*>(zb)[idx];
    float dx = a.x - b.x, dy = a.y - b.y, dz = a.z - b.z, dw = a.w - b.w;
    acc += dx * dx + dy * dy + dz * dz + dw * dw;
  }
  float tot = block_reduce(acc);
  if (threadIdx.x == 0) psums[blockIdx.x] = tot;
}

// XOR swizzle: element (k, col) of a KBx128 tile lives at u16 index col*64 + (k ^ sw(col)).
__device__ __forceinline__ int swz(int col) { return (((col >> 3) + col) & 7) << 3; }

__device__ __forceinline__ void store8(u16* lds, int c0, int kp, uint4 v0, uint4 v1) {
  const ushort* h0 = reinterpret_cast<const ushort*>(&v0);
  const ushort* h1 = reinterpret_cast<const ushort*>(&v1);
  #pragma unroll
  for (int j = 0; j < 8; ++j) {
    int col = c0 + j;
    unsigned w = (unsigned)h0[j] | ((unsigned)h1[j] << 16);
    *reinterpret_cast<unsigned*>(lds + col * KB + ((kp ^ swz(col)))) = w;
  }
}

__device__ __forceinline__ uint4 pack8(float4 x, float4 y) {
  uint4 o;
  o.x = f2bf(x.x) | (f2bf(x.y) << 16);
  o.y = f2bf(x.z) | (f2bf(x.w) << 16);
  o.z = f2bf(y.x) | (f2bf(y.y) << 16);
  o.w = f2bf(y.z) | (f2bf(y.w) << 16);
  return o;
}

// Kernel 2: gram with PERM-GATHER staging from za (f32 -> bf16 in registers).
// Row set for mat m = perm[m*HALF ..): gram is row-order invariant, so staging rows
// in perm order computes the exact z1/z2 grams with no materialization. Per-block
// perm slice pre-staged into LDS. Same swizzled-LDS MFMA core + bf16 parts as r9.
__global__ __launch_bounds__(256) void gram_kernel(const float* __restrict__ za,
                                                   const int* __restrict__ perm,
                                                   u16* __restrict__ parts) {
  int b = blockIdx.x;
  int mat = b & 1;
  int rest = b >> 1;
  int slice = rest & (NSLICE - 1);
  int tile = rest >> NSLOG2;  // 0..9 upper-tri
  int bi, bj;
  if (tile < 4)      { bi = 0; bj = tile; }
  else if (tile < 7) { bi = 1; bj = tile - 3; }
  else if (tile < 9) { bi = 2; bj = tile - 5; }
  else               { bi = 3; bj = 3; }
  int ti = bi * 128, tj = bj * 128;
  bool dual = (ti != tj);
  u16* P = parts + ((size_t)(mat * NSLICE + slice)) * (DDIM * DDIM);

  __shared__ u16 ldsA[128 * KB];
  __shared__ u16 ldsB[128 * KB];
  __shared__ int plds[512];
  const u16* ldsBp = dual ? ldsB : ldsA;

  int t = threadIdx.x;
  int lane = t & 63;
  int wave = t >> 6;
  int wrow = (wave >> 1) * 64;
  int wcol = (wave & 1) * 64;
  int g = lane >> 4;
  int c = lane & 15;
  int h = lane >> 4;
  int c0 = (lane & 15) << 3;
  int kp0 = 8 * wave + 2 * h;  // even row in [0,32)

  int pbase = mat * HALF + slice * 512;
  plds[t] = perm[pbase + t];
  plds[t + 256] = perm[pbase + t + 256];
  __syncthreads();

  f32x4 acc[4][4];
  #pragma unroll
  for (int m = 0; m < 4; ++m)
    #pragma unroll
    for (int n = 0; n < 4; ++n)
      #pragma unroll
      for (int r = 0; r < 4; ++r) acc[m][n][r] = 0.0f;

  float4 xa0, xa1, xa2, xa3, xa4, xa5, xa6, xa7;
  float4 xb0, xb1, xb2, xb3, xb4, xb5, xb6, xb7;
  float4 ya0, ya1, ya2, ya3, ya4, ya5, ya6, ya7;
  float4 yb0, yb1, yb2, yb3, yb4, yb5, yb6, yb7;

#define GLOAD(p, kkv) { \
    int r0 = plds[(kkv) + kp0], r1 = plds[(kkv) + kp0 + 1]; \
    int r2 = plds[(kkv) + kp0 + 32], r3 = plds[(kkv) + kp0 + 33]; \
    const float* q0 = za + (size_t)r0 * DDIM; \
    const float* q1 = za + (size_t)r1 * DDIM; \
    const float* q2 = za + (size_t)r2 * DDIM; \
    const float* q3 = za + (size_t)r3 * DDIM; \
    p##a0 = *reinterpret_cast<const float4*>(q0 + ti + c0); \
    p##a1 = *reinterpret_cast<const float4*>(q0 + ti + c0 + 4); \
    p##a2 = *reinterpret_cast<const float4*>(q1 + ti + c0); \
    p##a3 = *reinterpret_cast<const float4*>(q1 + ti + c0 + 4); \
    p##a4 = *reinterpret_cast<const float4*>(q2 + ti + c0); \
    p##a5 = *reinterpret_cast<const float4*>(q2 + ti + c0 + 4); \
    p##a6 = *reinterpret_cast<const float4*>(q3 + ti + c0); \
    p##a7 = *reinterpret_cast<const float4*>(q3 + ti + c0 + 4); \
    if (dual) { \
      p##b0 = *reinterpret_cast<const float4*>(q0 + tj + c0); \
      p##b1 = *reinterpret_cast<const float4*>(q0 + tj + c0 + 4); \
      p##b2 = *reinterpret_cast<const float4*>(q1 + tj + c0); \
      p##b3 = *reinterpret_cast<const float4*>(q1 + tj + c0 + 4); \
      p##b4 = *reinterpret_cast<const float4*>(q2 + tj + c0); \
      p##b5 = *reinterpret_cast<const float4*>(q2 + tj + c0 + 4); \
      p##b6 = *reinterpret_cast<const float4*>(q3 + tj + c0); \
      p##b7 = *reinterpret_cast<const float4*>(q3 + tj + c0 + 4); \
    } }

#define GSTORE(p) { \
    store8(ldsA, c0, kp0, pack8(p##a0, p##a1), pack8(p##a2, p##a3)); \
    store8(ldsA, c0, kp0 + 32, pack8(p##a4, p##a5), pack8(p##a6, p##a7)); \
    if (dual) { \
      store8(ldsB, c0, kp0, pack8(p##b0, p##b1), pack8(p##b2, p##b3)); \
      store8(ldsB, c0, kp0 + 32, pack8(p##b4, p##b5), pack8(p##b6, p##b7)); \
    } }

#define COMPUTE() { \
    _Pragma("unroll") \
    for (int ks = 0; ks < KB; ks += 32) { \
      s16x8 afr[4], bfr[4]; \
      _Pragma("unroll") \
      for (int m = 0; m < 4; ++m) { \
        int colA = wrow + m * 16 + c; \
        afr[m] = *reinterpret_cast<const s16x8*>(ldsA + colA * KB + ((ks + 8 * g) ^ swz(colA))); \
        int colB = wcol + m * 16 + c; \
        bfr[m] = *reinterpret_cast<const s16x8*>(ldsBp + colB * KB + ((ks + 8 * g) ^ swz(colB))); \
      } \
      _Pragma("unroll") \
      for (int m = 0; m < 4; ++m) \
        _Pragma("unroll") \
        for (int n = 0; n < 4; ++n) \
          acc[m][n] = __builtin_amdgcn_mfma_f32_16x16x32_bf16(afr[m], bfr[n], acc[m][n], 0, 0, 0); \
    } }

  GLOAD(x, 0);
  for (int kk = 0; kk < 512; kk += 2 * KB) {
    __syncthreads();
    GSTORE(x);
    __syncthreads();
    GLOAD(y, kk + KB);
    COMPUTE();
    __syncthreads();
    GSTORE(y);
    __syncthreads();
    if (kk + 2 * KB < 512) GLOAD(x, kk + 2 * KB);
    COMPUTE();
  }
#undef GLOAD
#undef GSTORE
#undef COMPUTE

  #pragma unroll
  for (int m = 0; m < 4; ++m)
    #pragma unroll
    for (int n = 0; n < 4; ++n)
      #pragma unroll
      for (int r = 0; r < 4; ++r) {
        int orow = ti + wrow + m * 16 + 4 * g + r;
        int ocol = tj + wcol + n * 16 + c;
        P[orow * DDIM + ocol] = (u16)f2bf(acc[m][n][r]);
      }
}

// Kernel 3: sum bf16 split-K partials over the triangle, scale by 1/(half-1), write full
// symmetric f32 cov (transposed scalar stores for the lower off-diag blocks).
__global__ void reduce_parts_kernel(const u16* __restrict__ parts, float* __restrict__ cov) {
  int idx = blockIdx.x * 256 + threadIdx.x;  // 0..81919
  int mat = (idx >= 40960) ? 1 : 0;
  int tl = idx - mat * 40960;
  int region = tl >> 12;  // 0..9
  int o = tl & 4095;
  int bi, bj;
  if (region < 4)      { bi = 0; bj = region; }
  else if (region < 7) { bi = 1; bj = region - 3; }
  else if (region < 9) { bi = 2; bj = region - 5; }
  else                 { bi = 3; bj = 3; }
  int r = bi * 128 + (o >> 5);
  int cc = bj * 128 + ((o & 31) << 2);
  const u16* base = parts + (size_t)mat * NSLICE * (DDIM * DDIM);
  float sx = 0.f, sy = 0.f, sz = 0.f, sw = 0.f;
  #pragma unroll 4
  for (int j = 0; j < NSLICE; ++j) {
    ushort4 v = *reinterpret_cast<const ushort4*>(base + (size_t)j * (DDIM * DDIM) + r * DDIM + cc);
    sx += bf2f(v.x); sy += bf2f(v.y); sz += bf2f(v.z); sw += bf2f(v.w);
  }
  const float inv = 1.0f / 16383.0f;
  sx *= inv; sy *= inv; sz *= inv; sw *= inv;
  float* cv = cov + (size_t)mat * (DDIM * DDIM);
  float4 ov; ov.x = sx; ov.y = sy; ov.z = sz; ov.w = sw;
  *reinterpret_cast<float4*>(cv + r * DDIM + cc) = ov;
  if (bi != bj) {
    cv[(cc + 0) * DDIM + r] = sx;
    cv[(cc + 1) * DDIM + r] = sy;
    cv[(cc + 2) * DDIM + r] = sz;
    cv[(cc + 3) * DDIM + r] = sw;
  }
}

// Kernel 4a: partial E tiles. grid = 16x16 tiles x CSLICE k-slices, LDS-staged panels,
// I-subtraction folded into staging. Partials to pcov (reuses parts region).
__global__ __launch_bounds__(256) void covdiff_part_kernel(const float* __restrict__ cov,
                                                           float* __restrict__ pcov) {
  int bid = blockIdx.x;
  int bx = bid & 15, by = (bid >> 4) & 15, sl = bid >> 8;
  int r0 = by * 32, c0 = bx * 32, ks = sl * 128;
  const float* c1 = cov;
  const float* c2 = cov + DDIM * DDIM;
  __shared__ float ldsA[32 * 132];
  __shared__ float ldsB[128 * 33];
  int t = threadIdx.x;
  #pragma unroll
  for (int j = 0; j < 4; ++j) {
    int f4 = t + 256 * j;   // 0..1023
    int row = f4 >> 5;      // 0..31
    int k4 = (f4 & 31) << 2;
    float4 v = *reinterpret_cast<const float4*>(c1 + (size_t)(r0 + row) * DDIM + ks + k4);
    int gr = r0 + row;
    if (gr == ks + k4 + 0) v.x -= 1.f;
    if (gr == ks + k4 + 1) v.y -= 1.f;
    if (gr == ks + k4 + 2) v.z -= 1.f;
    if (gr == ks + k4 + 3) v.w -= 1.f;
    *reinterpret_cast<float4*>(&ldsA[row * 132 + k4]) = v;
  }
  {
    int c = t & 31;
    int kb = t >> 5;  // 0..7
    #pragma unroll
    for (int j = 0; j < 16; ++j) {
      int k = kb + 8 * j;
      float v = c2[(size_t)(ks + k) * DDIM + c0 + c];
      if (ks + k == c0 + c) v -= 1.f;
      ldsB[k * 33 + c] = v;
    }
  }
  __syncthreads();
  int col = t & 31;
  int ty = t >> 5;  // 0..7 -> rows ty*4 + 0..3
  float e0 = 0.f, e1 = 0.f, e2 = 0.f, e3 = 0.f;
  #pragma unroll 4
  for (int k = 0; k < 128; ++k) {
    float bv = ldsB[k * 33 + col];
    e0 = fmaf(ldsA[(ty * 4 + 0) * 132 + k], bv, e0);
    e1 = fmaf(ldsA[(ty * 4 + 1) * 132 + k], bv, e1);
    e2 = fmaf(ldsA[(ty * 4 + 2) * 132 + k], bv, e2);
    e3 = fmaf(ldsA[(ty * 4 + 3) * 132 + k], bv, e3);
  }
  float* P = pcov + (size_t)sl * (DDIM * DDIM);
  P[(r0 + ty * 4 + 0) * DDIM + c0 + col] = e0;
  P[(r0 + ty * 4 + 1) * DDIM + c0 + col] = e1;
  P[(r0 + ty * 4 + 2) * DDIM + c0 + col] = e2;
  P[(r0 + ty * 4 + 3) * DDIM + c0 + col] = e3;
}

// Kernel 4b: sum slices, square, per-block partials to psums2.
__global__ void covred_kernel(const float* __restrict__ pcov, float* __restrict__ psums2) {
  int idx = blockIdx.x * 256 + threadIdx.x;  // 0..65535 float4 slots
  float sx = 0.f, sy = 0.f, sz = 0.f, sw = 0.f;
  #pragma unroll
  for (int j = 0; j < CSLICE; ++j) {
    float4 v = reinterpret_cast<const float4*>(pcov)[idx + j * 65536];
    sx += v.x; sy += v.y; sz += v.z; sw += v.w;
  }
  float q = sx * sx + sy * sy + sz * sz + sw * sw;
  float tot = block_reduce(q);
  if (threadIdx.x == 0) psums2[blockIdx.x] = tot;
}

// Kernel 5: final reduction of 2048 repr partials + 256 frob partials.
__global__ void finalize_kernel(const float* __restrict__ psums,
                                const float* __restrict__ psums2,
                                float* __restrict__ out) {
  int t = threadIdx.x;
  float a = 0.f;
  #pragma unroll
  for (int j = 0; j < 8; ++j) a += psums[t + 256 * j];
  float b = psums2[t];
  float ta = block_reduce(a);
  __syncthreads();
  float tb = block_reduce(b);
  if (t == 0) out[0] = 25.0f * (ta / 16777216.0f) + sqrtf(tb);
}

extern "C" void kernel_launch(void* const* d_in, const int* in_sizes, int n_in,
                              void* d_out, int out_size, void* d_ws, size_t ws_size,
                              hipStream_t stream) {
  const float* za = (const float*)d_in[0];
  const float* zb = (const float*)d_in[1];
  const int* perm = (const int*)d_in[2];
  float* out = (float*)d_out;
  char* ws = (char*)d_ws;

  // workspace: psums(8KB) | psums2(1KB) | pad | cov(2MB) | parts bf16(32MB, reused as pcov)
  float* psums = (float*)ws;             // 2048 floats
  float* psums2 = (float*)(ws + 8192);   // 256 floats
  size_t off = 16384;
  float* cov = (float*)(ws + off);
  off += (size_t)2 * DDIM * DDIM * 4;
  u16* parts = (u16*)(ws + off);
  float* pcov = (float*)parts;  // parts dead after reduce_parts; CSLICE*1MB <= 32MB

  repr_kernel<<<2048, 256, 0, stream>>>(za, zb, psums);
  gram_kernel<<<2 * 10 * NSLICE, 256, 0, stream>>>(za, perm, parts);
  reduce_parts_kernel<<<320, 256, 0, stream>>>(parts, cov);
  covdiff_part_kernel<<<16 * 16 * CSLICE, 256, 0, stream>>>(cov, pcov);
  covred_kernel<<<256, 256, 0, stream>>>(pcov, psums2);
  finalize_kernel<<<1, 256, 0, stream>>>(psums, psums2, out);
}

// Round 12
// 77.941 us; speedup vs baseline: 1.3620x; 1.1142x over previous
//
#include <hip/hip_runtime.h>
#include <math.h>

typedef unsigned short u16;
typedef __attribute__((ext_vector_type(8))) short s16x8;
typedef __attribute__((ext_vector_type(4))) float f32x4;

#define NROWS 32768
#define DDIM 512
#define HALF 16384
#define KB 64
#define CSLICE 4
#define NSLICE 16
#define NSLOG2 4

__device__ __forceinline__ u16 f2bf(float f) {
  unsigned int u = __float_as_uint(f);
  unsigned int rounding = 0x7FFFu + ((u >> 16) & 1u);
  u += rounding;
  return (u16)(u >> 16);
}

__device__ __forceinline__ float bf2f(u16 h) {
  return __uint_as_float(((unsigned)h) << 16);
}

__device__ __forceinline__ float block_reduce(float v) {
  #pragma unroll
  for (int o = 32; o > 0; o >>= 1) v += __shfl_down(v, o);
  __shared__ float red[4];
  int w = threadIdx.x >> 6;
  if ((threadIdx.x & 63) == 0) red[w] = v;
  __syncthreads();
  return red[0] + red[1] + red[2] + red[3];
}

// Kernel 0: inverse permutation. inv[perm[i]] = i.
__global__ void inv_kernel(const int* __restrict__ perm, int* __restrict__ inv) {
  int i = blockIdx.x * 256 + threadIdx.x;
  inv[perm[i]] = i;
}

__device__ __forceinline__ float chunk_proc(float4 a0, float4 a1, float4 b0, float4 b1,
                                            int r, int c8, u16* z1, u16* z2) {
  uint4 o;
  o.x = (unsigned)f2bf(a0.x) | ((unsigned)f2bf(a0.y) << 16);
  o.y = (unsigned)f2bf(a0.z) | ((unsigned)f2bf(a0.w) << 16);
  o.z = (unsigned)f2bf(a1.x) | ((unsigned)f2bf(a1.y) << 16);
  o.w = (unsigned)f2bf(a1.z) | ((unsigned)f2bf(a1.w) << 16);
  u16* dst = (r < HALF) ? (z1 + (size_t)r * DDIM + c8) : (z2 + (size_t)(r - HALF) * DDIM + c8);
  *reinterpret_cast<uint4*>(dst) = o;
  float dx = a0.x - b0.x, dy = a0.y - b0.y, dz = a0.z - b0.z, dw = a0.w - b0.w;
  float ex = a1.x - b1.x, ey = a1.y - b1.y, ez = a1.z - b1.z, ew = a1.w - b1.w;
  return dx*dx + dy*dy + dz*dz + dw*dw + ex*ex + ey*ey + ez*ez + ew*ew;
}

// Kernel 1: sequential read of z_a/z_b, fused repr partial, bf16 convert, scattered row
// write into z1/z2 by rank inv[row]. r11 measured pure-read=43us, so this (50us,
// 160 MB R+W) sits ~7us over the chip's ~3.2 TB/s total-traffic wall. Final form.
__global__ __launch_bounds__(256) void scatter_repr_kernel(
    const float* __restrict__ za, const float* __restrict__ zb, const int* __restrict__ inv,
    u16* __restrict__ z1, u16* __restrict__ z2, float* __restrict__ psums) {
  int t = threadIdx.x;
  float acc = 0.0f;
  #pragma unroll
  for (int i = 0; i < 4; ++i) {
    int chunk = (i * 2048 + blockIdx.x) * 256 + t;
    int row = chunk >> 6;
    int c8 = (chunk & 63) << 3;
    const float4* pa = reinterpret_cast<const float4*>(za + (size_t)row * DDIM + c8);
    const float4* pb = reinterpret_cast<const float4*>(zb + (size_t)row * DDIM + c8);
    float4 a0 = pa[0], a1 = pa[1];
    float4 b0 = pb[0], b1 = pb[1];
    int r = inv[row];
    acc += chunk_proc(a0, a1, b0, b1, r, c8, z1, z2);
  }
  float tot = block_reduce(acc);
  if (t == 0) psums[blockIdx.x] = tot;
}

// XOR swizzle: element (k, col) of a KBx128 tile lives at u16 index col*64 + (k ^ sw(col)).
__device__ __forceinline__ int swz(int col) { return (((col >> 3) + col) & 7) << 3; }

__device__ __forceinline__ void store8(u16* lds, int c0, int kp, uint4 v0, uint4 v1) {
  const ushort* h0 = reinterpret_cast<const ushort*>(&v0);
  const ushort* h1 = reinterpret_cast<const ushort*>(&v1);
  #pragma unroll
  for (int j = 0; j < 8; ++j) {
    int col = c0 + j;
    unsigned w = (unsigned)h0[j] | ((unsigned)h1[j] << 16);
    *reinterpret_cast<unsigned*>(lds + col * KB + ((kp ^ swz(col)))) = w;
  }
}

// Kernel 2: gram partials (bf16), upper-triangular 128x128 tiles, reg-staged 2-phase
// double buffer. NSLICE=16 (vs r9's 32) halves the parts round-trip traffic; kspan
// 1024 = 8 double-buffered K-iterations per block, 320 blocks (one co-residency round).
__global__ __launch_bounds__(256) void gram_kernel(const u16* __restrict__ z1,
                                                   const u16* __restrict__ z2,
                                                   u16* __restrict__ parts) {
  int b = blockIdx.x;
  int mat = b & 1;
  int rest = b >> 1;
  int slice = rest & (NSLICE - 1);
  int tile = rest >> NSLOG2;  // 0..9 upper-tri
  int bi, bj;
  if (tile < 4)      { bi = 0; bj = tile; }
  else if (tile < 7) { bi = 1; bj = tile - 3; }
  else if (tile < 9) { bi = 2; bj = tile - 5; }
  else               { bi = 3; bj = 3; }
  int ti = bi * 128, tj = bj * 128;
  const u16* Z = mat ? z2 : z1;
  bool dual = (ti != tj);
  u16* P = parts + ((size_t)(mat * NSLICE + slice)) * (DDIM * DDIM);

  __shared__ u16 ldsA[128 * KB];
  __shared__ u16 ldsB[128 * KB];
  const u16* ldsBp = dual ? ldsB : ldsA;

  int t = threadIdx.x;
  int lane = t & 63;
  int wave = t >> 6;
  int wrow = (wave >> 1) * 64;
  int wcol = (wave & 1) * 64;
  int g = lane >> 4;
  int c = lane & 15;
  int h = lane >> 4;
  int c0 = (lane & 15) << 3;
  int kp0 = 8 * wave + 2 * h;  // even row in [0,32)

  f32x4 acc[4][4];
  #pragma unroll
  for (int m = 0; m < 4; ++m)
    #pragma unroll
    for (int n = 0; n < 4; ++n)
      #pragma unroll
      for (int r = 0; r < 4; ++r) acc[m][n][r] = 0.0f;

  uint4 xa0, xa1, xa2, xa3, xb0, xb1, xb2, xb3;
  uint4 ya0, ya1, ya2, ya3, yb0, yb1, yb2, yb3;

#define GLOAD(p, kkv) { \
    const u16* s0 = Z + (size_t)((kkv) + kp0) * DDIM; \
    const u16* s1 = Z + (size_t)((kkv) + kp0 + 32) * DDIM; \
    p##a0 = *reinterpret_cast<const uint4*>(s0 + ti + c0); \
    p##a1 = *reinterpret_cast<const uint4*>(s0 + DDIM + ti + c0); \
    p##a2 = *reinterpret_cast<const uint4*>(s1 + ti + c0); \
    p##a3 = *reinterpret_cast<const uint4*>(s1 + DDIM + ti + c0); \
    if (dual) { \
      p##b0 = *reinterpret_cast<const uint4*>(s0 + tj + c0); \
      p##b1 = *reinterpret_cast<const uint4*>(s0 + DDIM + tj + c0); \
      p##b2 = *reinterpret_cast<const uint4*>(s1 + tj + c0); \
      p##b3 = *reinterpret_cast<const uint4*>(s1 + DDIM + tj + c0); \
    } }

#define GSTORE(p) { \
    store8(ldsA, c0, kp0, p##a0, p##a1); \
    store8(ldsA, c0, kp0 + 32, p##a2, p##a3); \
    if (dual) { \
      store8(ldsB, c0, kp0, p##b0, p##b1); \
      store8(ldsB, c0, kp0 + 32, p##b2, p##b3); \
    } }

#define COMPUTE() { \
    _Pragma("unroll") \
    for (int ks = 0; ks < KB; ks += 32) { \
      s16x8 afr[4], bfr[4]; \
      _Pragma("unroll") \
      for (int m = 0; m < 4; ++m) { \
        int colA = wrow + m * 16 + c; \
        afr[m] = *reinterpret_cast<const s16x8*>(ldsA + colA * KB + ((ks + 8 * g) ^ swz(colA))); \
        int colB = wcol + m * 16 + c; \
        bfr[m] = *reinterpret_cast<const s16x8*>(ldsBp + colB * KB + ((ks + 8 * g) ^ swz(colB))); \
      } \
      _Pragma("unroll") \
      for (int m = 0; m < 4; ++m) \
        _Pragma("unroll") \
        for (int n = 0; n < 4; ++n) \
          acc[m][n] = __builtin_amdgcn_mfma_f32_16x16x32_bf16(afr[m], bfr[n], acc[m][n], 0, 0, 0); \
    } }

  const int kspan = HALF >> NSLOG2;  // 1024
  const int k0 = slice * kspan;
  GLOAD(x, k0);
  for (int kk = k0; kk < k0 + kspan; kk += 2 * KB) {
    __syncthreads();
    GSTORE(x);
    __syncthreads();
    GLOAD(y, kk + KB);
    COMPUTE();
    __syncthreads();
    GSTORE(y);
    __syncthreads();
    if (kk + 2 * KB < k0 + kspan) GLOAD(x, kk + 2 * KB);
    COMPUTE();
  }
#undef GLOAD
#undef GSTORE
#undef COMPUTE

  #pragma unroll
  for (int m = 0; m < 4; ++m)
    #pragma unroll
    for (int n = 0; n < 4; ++n)
      #pragma unroll
      for (int r = 0; r < 4; ++r) {
        int orow = ti + wrow + m * 16 + 4 * g + r;
        int ocol = tj + wcol + n * 16 + c;
        P[orow * DDIM + ocol] = f2bf(acc[m][n][r]);
      }
}

// Kernel 3: sum bf16 split-K partials over the triangle, scale by 1/(half-1), write full
// symmetric f32 cov (transposed scalar stores for the lower off-diag blocks).
__global__ void reduce_parts_kernel(const u16* __restrict__ parts, float* __restrict__ cov) {
  int idx = blockIdx.x * 256 + threadIdx.x;  // 0..81919
  int mat = (idx >= 40960) ? 1 : 0;
  int tl = idx - mat * 40960;
  int region = tl >> 12;  // 0..9
  int o = tl & 4095;
  int bi, bj;
  if (region < 4)      { bi = 0; bj = region; }
  else if (region < 7) { bi = 1; bj = region - 3; }
  else if (region < 9) { bi = 2; bj = region - 5; }
  else                 { bi = 3; bj = 3; }
  int r = bi * 128 + (o >> 5);
  int cc = bj * 128 + ((o & 31) << 2);
  const u16* base = parts + (size_t)mat * NSLICE * (DDIM * DDIM);
  float sx = 0.f, sy = 0.f, sz = 0.f, sw = 0.f;
  #pragma unroll 4
  for (int j = 0; j < NSLICE; ++j) {
    ushort4 v = *reinterpret_cast<const ushort4*>(base + (size_t)j * (DDIM * DDIM) + r * DDIM + cc);
    sx += bf2f(v.x); sy += bf2f(v.y); sz += bf2f(v.z); sw += bf2f(v.w);
  }
  const float inv = 1.0f / 16383.0f;
  sx *= inv; sy *= inv; sz *= inv; sw *= inv;
  float* cv = cov + (size_t)mat * (DDIM * DDIM);
  float4 ov; ov.x = sx; ov.y = sy; ov.z = sz; ov.w = sw;
  *reinterpret_cast<float4*>(cv + r * DDIM + cc) = ov;
  if (bi != bj) {
    cv[(cc + 0) * DDIM + r] = sx;
    cv[(cc + 1) * DDIM + r] = sy;
    cv[(cc + 2) * DDIM + r] = sz;
    cv[(cc + 3) * DDIM + r] = sw;
  }
}

// Kernel 4a: partial E tiles. grid = 16x16 tiles x CSLICE k-slices, LDS-staged panels,
// I-subtraction folded into staging. Partials to pcov (reused z1 region).
__global__ __launch_bounds__(256) void covdiff_part_kernel(const float* __restrict__ cov,
                                                           float* __restrict__ pcov) {
  int bid = blockIdx.x;
  int bx = bid & 15, by = (bid >> 4) & 15, sl = bid >> 8;
  int r0 = by * 32, c0 = bx * 32, ks = sl * 128;
  const float* c1 = cov;
  const float* c2 = cov + DDIM * DDIM;
  __shared__ float ldsA[32 * 132];
  __shared__ float ldsB[128 * 33];
  int t = threadIdx.x;
  #pragma unroll
  for (int j = 0; j < 4; ++j) {
    int f4 = t + 256 * j;   // 0..1023
    int row = f4 >> 5;      // 0..31
    int k4 = (f4 & 31) << 2;
    float4 v = *reinterpret_cast<const float4*>(c1 + (size_t)(r0 + row) * DDIM + ks + k4);
    int gr = r0 + row;
    if (gr == ks + k4 + 0) v.x -= 1.f;
    if (gr == ks + k4 + 1) v.y -= 1.f;
    if (gr == ks + k4 + 2) v.z -= 1.f;
    if (gr == ks + k4 + 3) v.w -= 1.f;
    *reinterpret_cast<float4*>(&ldsA[row * 132 + k4]) = v;
  }
  {
    int c = t & 31;
    int kb = t >> 5;  // 0..7
    #pragma unroll
    for (int j = 0; j < 16; ++j) {
      int k = kb + 8 * j;
      float v = c2[(size_t)(ks + k) * DDIM + c0 + c];
      if (ks + k == c0 + c) v -= 1.f;
      ldsB[k * 33 + c] = v;
    }
  }
  __syncthreads();
  int col = t & 31;
  int ty = t >> 5;  // 0..7 -> rows ty*4 + 0..3
  float e0 = 0.f, e1 = 0.f, e2 = 0.f, e3 = 0.f;
  #pragma unroll 4
  for (int k = 0; k < 128; ++k) {
    float bv = ldsB[k * 33 + col];
    e0 = fmaf(ldsA[(ty * 4 + 0) * 132 + k], bv, e0);
    e1 = fmaf(ldsA[(ty * 4 + 1) * 132 + k], bv, e1);
    e2 = fmaf(ldsA[(ty * 4 + 2) * 132 + k], bv, e2);
    e3 = fmaf(ldsA[(ty * 4 + 3) * 132 + k], bv, e3);
  }
  float* P = pcov + (size_t)sl * (DDIM * DDIM);
  P[(r0 + ty * 4 + 0) * DDIM + c0 + col] = e0;
  P[(r0 + ty * 4 + 1) * DDIM + c0 + col] = e1;
  P[(r0 + ty * 4 + 2) * DDIM + c0 + col] = e2;
  P[(r0 + ty * 4 + 3) * DDIM + c0 + col] = e3;
}

// Kernel 4b: sum slices, square, per-block partials to psums2.
__global__ void covred_kernel(const float* __restrict__ pcov, float* __restrict__ psums2) {
  int idx = blockIdx.x * 256 + threadIdx.x;  // 0..65535 float4 slots
  float sx = 0.f, sy = 0.f, sz = 0.f, sw = 0.f;
  #pragma unroll
  for (int j = 0; j < CSLICE; ++j) {
    float4 v = reinterpret_cast<const float4*>(pcov)[idx + j * 65536];
    sx += v.x; sy += v.y; sz += v.z; sw += v.w;
  }
  float q = sx * sx + sy * sy + sz * sz + sw * sw;
  float tot = block_reduce(q);
  if (threadIdx.x == 0) psums2[blockIdx.x] = tot;
}

// Kernel 5: final reduction of 2048 repr partials + 256 frob partials.
__global__ void finalize_kernel(const float* __restrict__ psums,
                                const float* __restrict__ psums2,
                                float* __restrict__ out) {
  int t = threadIdx.x;
  float a = 0.f;
  #pragma unroll
  for (int j = 0; j < 8; ++j) a += psums[t + 256 * j];
  float b = psums2[t];
  float ta = block_reduce(a);
  __syncthreads();
  float tb = block_reduce(b);
  if (t == 0) out[0] = 25.0f * (ta / 16777216.0f) + sqrtf(tb);
}

extern "C" void kernel_launch(void* const* d_in, const int* in_sizes, int n_in,
                              void* d_out, int out_size, void* d_ws, size_t ws_size,
                              hipStream_t stream) {
  const float* za = (const float*)d_in[0];
  const float* zb = (const float*)d_in[1];
  const int* perm = (const int*)d_in[2];
  float* out = (float*)d_out;
  char* ws = (char*)d_ws;

  // workspace: psums(8KB)+psums2(1KB)+pad | parts bf16(16MB) | cov(2MB) | z1,z2(32MB) | inv(128KB)
  float* psums = (float*)ws;            // 2048 floats
  float* psums2 = (float*)(ws + 8192);  // 256 floats
  size_t off = 16384;
  u16* parts = (u16*)(ws + off);
  off += (size_t)2 * NSLICE * DDIM * DDIM * 2;
  float* cov = (float*)(ws + off);
  off += (size_t)2 * DDIM * DDIM * 4;
  u16* z1 = (u16*)(ws + off);
  u16* z2 = z1 + (size_t)HALF * DDIM;
  float* pcov = (float*)z1;  // reused after gram consumes z1/z2 (CSLICE*1MB <= 16MB)
  off += (size_t)2 * HALF * DDIM * 2;
  int* inv = (int*)(ws + off);

  inv_kernel<<<NROWS / 256, 256, 0, stream>>>(perm, inv);
  scatter_repr_kernel<<<2048, 256, 0, stream>>>(za, zb, inv, z1, z2, psums);
  gram_kernel<<<2 * 10 * NSLICE, 256, 0, stream>>>(z1, z2, parts);
  reduce_parts_kernel<<<320, 256, 0, stream>>>(parts, cov);
  covdiff_part_kernel<<<16 * 16 * CSLICE, 256, 0, stream>>>(cov, pcov);
  covred_kernel<<<256, 256, 0, stream>>>(pcov, psums2);
  finalize_kernel<<<1, 256, 0, stream>>>(psums, psums2, out);
}